// Round 1
// baseline (10646.488 us; speedup 1.0000x reference)
//
#include <hip/hip_runtime.h>
#include <hip/hip_bf16.h>

#define Bn   1024
#define Tn   730
#define INn  64
#define Hn   512
#define Kn   576      // INn + Hn
#define G4n  2048     // 4*Hn

typedef __bf16 bf16x8 __attribute__((ext_vector_type(8)));
typedef float  f32x4  __attribute__((ext_vector_type(4)));

#define AS_G __attribute__((address_space(1)))
#define AS_L __attribute__((address_space(3)))

// zT layout: [64 rows][4 gates * 36], row stride 140 words (140%8==4 -> q varies bank; %4==0 -> b128-aligned)
#define ZSTR 140
#define GSTR 36

// ---------------- weight pre-pack: Wc[row][k] bf16, row = gate*512+j, k over [x|h] ----------
__global__ void convert_weights(const float* __restrict__ Wih,
                                const float* __restrict__ Whh,
                                __bf16* __restrict__ Wc) {
    int idx = blockIdx.x * 256 + threadIdx.x;
    if (idx >= G4n * Kn) return;
    int row = idx / Kn;
    int k   = idx - row * Kn;
    float v = (k < INn) ? Wih[row * INn + k] : Whh[row * Hn + (k - INn)];
    Wc[idx] = (__bf16)v;
}

__device__ __forceinline__ float sigf(float x)   { return 1.0f / (1.0f + __expf(-x)); }
__device__ __forceinline__ float tanhf_f(float x){ return 2.0f * sigf(2.0f * x) - 1.0f; }

// ---------------- persistent LSTM scan ----------------
// 256 blocks x 256 threads (4 waves). Block = (mi: 64 batch rows) x (nj: 32 h-cols).
// Wave w = gate w: holds 32 cols x 576 k of weights in 144 VGPRs.
// h staging: global_load_lds DMA with PLAIN cached loads; freshness via per-step
// agent acquire fence (buffer_inv sc1 -> inv L1+L2). h writes stay relaxed-agent
// atomics (sc0/sc1 write-through to IC), drained by __syncthreads before arrive.
// Correctness is XCD-mapping independent: every block invalidates its own caches
// after the group barrier and before reading h.
__global__ __launch_bounds__(256, 1) void lstm_persist(
    const float* __restrict__ xd,     // [B,T,IN]
    const float* __restrict__ bias,   // [4H]
    const __bf16* __restrict__ Wc,    // [4H][Kn]
    __bf16* __restrict__ h0,          // [B,H] buffer A (final h lands here)
    __bf16* __restrict__ h1,          // [B,H] buffer B
    unsigned int* __restrict__ bar)   // 16 groups x 32 uints (128B stride)
{
    // LDS: A-tile (fragment order) 73728B + zT 64*140*4 = 35840B
    __shared__ __align__(16) char smem[73728 + 35840];
    bf16x8* aTile = (bf16x8*)smem;
    float*  zT    = (float*)(smem + 73728);

    const int blk  = blockIdx.x;
    const int xcd  = blk & 7;
    const int slot = blk >> 3;
    const int mi   = xcd * 2 + (slot & 1);
    const int nj   = slot >> 1;
    const int m0   = mi << 6;
    const int j0   = nj << 5;

    const int tid  = threadIdx.x;              // 0..255
    const int wave = tid >> 6;                 // 0..3 == gate
    const int wv   = __builtin_amdgcn_readfirstlane(wave);  // scalar copy
    const int lane = tid & 63;
    const int q    = lane >> 4;
    const int l16  = lane & 15;

    // ---- resident weights: gate wv, cols j0 + js*16 + l16, 18 k-blocks: 144 VGPRs ----
    bf16x8 wreg[18][2];
    #pragma unroll
    for (int kb = 0; kb < 18; ++kb) {
        #pragma unroll
        for (int js = 0; js < 2; ++js)
            wreg[kb][js] = *(const bf16x8*)(Wc + (size_t)(wv * Hn + j0 + js * 16 + l16) * Kn
                                               + kb * 32 + q * 8);
    }
    // bias broadcast for acc init (per-lane output column)
    const float bini0 = bias[wv * Hn + j0 + 0 * 16 + l16];
    const float bini1 = bias[wv * Hn + j0 + 1 * 16 + l16];

    // ---- x-fragment closed form: wave w stages fragments i = xi0, xi0+9 ----
    // (kc = i*4+w: kb = kc%18 in {0,1}, rg = xrg0 + 2j)
    const int xi0  = (wv & 2) ? 4 : 0;
    const int xkb  = wv & 1;
    const int xrg0 = (wv & 2) ? 1 : 0;

    // ---- pointwise ownership: thread -> (1 row, 8 consecutive cols) ----
    const int pr   = tid >> 2;                 // 0..63
    const int pc8  = (tid & 3) << 3;           // 0,8,16,24
    const int prow = m0 + pr;
    float creg[8];
    #pragma unroll
    for (int i = 0; i < 8; ++i) creg[i] = 0.f;

    unsigned int* cnt = bar + (mi << 5);
    bool dead = false;

    // ---- prologue: stage x(t=0) ----
    {
        #pragma unroll
        for (int j = 0; j < 2; ++j) {
            const int row = m0 + (xrg0 + 2 * j) * 16 + l16;
            const float* xp = xd + (size_t)row * (Tn * INn) + xkb * 32 + q * 8;
            f32x4 lo = *(const f32x4*)xp;
            f32x4 hi = *(const f32x4*)(xp + 4);
            bf16x8 v;
            v[0] = (__bf16)lo[0]; v[1] = (__bf16)lo[1]; v[2] = (__bf16)lo[2]; v[3] = (__bf16)lo[3];
            v[4] = (__bf16)hi[0]; v[5] = (__bf16)hi[1]; v[6] = (__bf16)hi[2]; v[7] = (__bf16)hi[3];
            aTile[(xi0 + 9 * j) * 256 + tid] = v;
        }
    }

    for (int t = 0; t < Tn; ++t) {
        const __bf16* hread  = (t & 1) ? h1 : h0;
        __bf16*       hwrite = (t & 1) ? h0 : h1;

        // ---- phase 1: DMA h into aTile (16 of 18 fragments per wave) ----
        #pragma unroll
        for (int i = 0; i < 18; ++i) {
            const int kc = i * 4 + wv;         // scalar
            const int kb = kc % 18;
            const int rg = kc / 18;
            if (kb >= 2) {
                const __bf16* src = hread + (size_t)(m0 + rg * 16 + l16) * Hn
                                          + (kb * 32 + q * 8 - 64);
                char* dst = smem + i * 4096 + wv * 1024;   // wave-uniform; HW adds lane*16
                __builtin_amdgcn_global_load_lds((AS_G const unsigned int*)(const void*)src,
                                                 (AS_L unsigned int*)(void*)dst, 16, 0, 0);
            }
        }
        __syncthreads();   // drains DMA (vmcnt) + prev x ds_writes (lgkm)

        // ---- phase 2: MFMA, weights from registers, A from LDS ----
        f32x4 acc[4][2];
        #pragma unroll
        for (int rg = 0; rg < 4; ++rg) {
            acc[rg][0] = (f32x4){bini0, bini0, bini0, bini0};
            acc[rg][1] = (f32x4){bini1, bini1, bini1, bini1};
        }
        #pragma unroll
        for (int kb = 0; kb < 18; ++kb) {
            #pragma unroll
            for (int rg = 0; rg < 4; ++rg) {
                const bf16x8 af = aTile[(rg * 18 + kb) * 64 + lane];
                acc[rg][0] = __builtin_amdgcn_mfma_f32_16x16x32_bf16(af, wreg[kb][0], acc[rg][0], 0, 0, 0);
                acc[rg][1] = __builtin_amdgcn_mfma_f32_16x16x32_bf16(af, wreg[kb][1], acc[rg][1], 0, 0, 0);
            }
        }
        // z scatter: zT[row][gate*36 + col], conflict-friendly strides
        #pragma unroll
        for (int rg = 0; rg < 4; ++rg) {
            #pragma unroll
            for (int js = 0; js < 2; ++js) {
                #pragma unroll
                for (int r = 0; r < 4; ++r)
                    zT[(rg * 16 + q * 4 + r) * ZSTR + wv * GSTR + js * 16 + l16] = acc[rg][js][r];
            }
        }
        __syncthreads();

        // ---- phase 3: issue x(t+1) loads, pointwise under their latency ----
        f32x4 xlo0, xhi0, xlo1, xhi1;
        const bool do_x = (t + 1 < Tn);
        if (do_x) {
            const int row0 = m0 + (xrg0 + 0) * 16 + l16;
            const int row1 = m0 + (xrg0 + 2) * 16 + l16;
            const float* xp0 = xd + (size_t)row0 * (Tn * INn) + (size_t)(t + 1) * INn + xkb * 32 + q * 8;
            const float* xp1 = xd + (size_t)row1 * (Tn * INn) + (size_t)(t + 1) * INn + xkb * 32 + q * 8;
            xlo0 = *(const f32x4*)xp0;  xhi0 = *(const f32x4*)(xp0 + 4);
            xlo1 = *(const f32x4*)xp1;  xhi1 = *(const f32x4*)(xp1 + 4);
        }

        // gate pointwise; c in regs; h -> global via u64 write-through
        float zv[4][8];
        #pragma unroll
        for (int g = 0; g < 4; ++g) {
            f32x4 lo = *(const f32x4*)&zT[pr * ZSTR + g * GSTR + pc8];
            f32x4 hi = *(const f32x4*)&zT[pr * ZSTR + g * GSTR + pc8 + 4];
            zv[g][0] = lo[0]; zv[g][1] = lo[1]; zv[g][2] = lo[2]; zv[g][3] = lo[3];
            zv[g][4] = hi[0]; zv[g][5] = hi[1]; zv[g][6] = hi[2]; zv[g][7] = hi[3];
        }
        union { unsigned long long u[2]; __bf16 h[8]; } pk;
        #pragma unroll
        for (int cc = 0; cc < 8; ++cc) {
            const float cn = sigf(zv[1][cc]) * creg[cc]
                           + sigf(zv[0][cc]) * tanhf_f(zv[2][cc]);
            creg[cc] = cn;
            pk.h[cc] = (__bf16)(sigf(zv[3][cc]) * tanhf_f(cn));
        }
        unsigned long long* hp = (unsigned long long*)(hwrite + (size_t)prow * Hn + j0 + pc8);
        __hip_atomic_store(hp,     pk.u[0], __ATOMIC_RELAXED, __HIP_MEMORY_SCOPE_AGENT);
        __hip_atomic_store(hp + 1, pk.u[1], __ATOMIC_RELAXED, __HIP_MEMORY_SCOPE_AGENT);

        // finish x(t+1) staging (loads have had the pointwise phase to land)
        if (do_x) {
            bf16x8 v0, v1;
            v0[0] = (__bf16)xlo0[0]; v0[1] = (__bf16)xlo0[1]; v0[2] = (__bf16)xlo0[2]; v0[3] = (__bf16)xlo0[3];
            v0[4] = (__bf16)xhi0[0]; v0[5] = (__bf16)xhi0[1]; v0[6] = (__bf16)xhi0[2]; v0[7] = (__bf16)xhi0[3];
            v1[0] = (__bf16)xlo1[0]; v1[1] = (__bf16)xlo1[1]; v1[2] = (__bf16)xlo1[2]; v1[3] = (__bf16)xlo1[3];
            v1[4] = (__bf16)xhi1[0]; v1[5] = (__bf16)xhi1[1]; v1[6] = (__bf16)xhi1[2]; v1[7] = (__bf16)xhi1[3];
            aTile[(xi0 + 0) * 256 + tid] = v0;
            aTile[(xi0 + 9) * 256 + tid] = v1;
        }

        // ---- phase 4: group barrier (16 blocks sharing mi) ----
        __syncthreads();   // drains vmcnt(0): all write-through h stores at IC
        if (tid == 0) {
            __hip_atomic_fetch_add(cnt, 1u, __ATOMIC_RELAXED, __HIP_MEMORY_SCOPE_AGENT);
            if (!dead) {
                const unsigned int target = 16u * (unsigned int)(t + 1);
                int spins = 0;
                while (__hip_atomic_load(cnt, __ATOMIC_RELAXED, __HIP_MEMORY_SCOPE_AGENT) < target) {
                    __builtin_amdgcn_s_sleep(2);
                    if (++spins > 300000) { dead = true; break; }  // hang -> fast wrong-answer
                }
            }
        }
        __syncthreads();
        // acquire: inv L1+L2 so next step's cached h reads see IC-fresh data
        __builtin_amdgcn_fence(__ATOMIC_ACQUIRE, "agent");
    }
}

// ---------------- head: out[b] = relu(dot(h_T[b], Wl) + bl) ----------------
__global__ void head_kernel(const __bf16* __restrict__ h, const float* __restrict__ Wl,
                            const float* __restrict__ bl, float* __restrict__ out) {
    const int b = blockIdx.x;
    const int lane = threadIdx.x;  // 64 threads
    const __bf16* hp = h + (size_t)b * Hn;
    float s = 0.f;
    #pragma unroll
    for (int j = lane; j < Hn; j += 64) s += (float)hp[j] * Wl[j];
    #pragma unroll
    for (int off = 32; off > 0; off >>= 1) s += __shfl_down(s, off, 64);
    if (lane == 0) out[b] = fmaxf(s + bl[0], 0.0f);
}

extern "C" void kernel_launch(void* const* d_in, const int* in_sizes, int n_in,
                              void* d_out, int out_size, void* d_ws, size_t ws_size,
                              hipStream_t stream) {
    const float* xd  = (const float*)d_in[0];
    const float* Wih = (const float*)d_in[1];
    const float* Whh = (const float*)d_in[2];
    const float* b   = (const float*)d_in[3];
    const float* Wl  = (const float*)d_in[4];
    const float* bl  = (const float*)d_in[5];
    float* out = (float*)d_out;

    // ws layout:
    //   Wc  bf16 [2048][576] : 2,359,296 B
    //   h0  bf16 [1024][512] : 1,048,576 B
    //   h1  bf16 [1024][512] : 1,048,576 B
    //   bar u32  [16][32]    : 2,048 B
    char* ws = (char*)d_ws;
    __bf16* Wc = (__bf16*)ws;
    __bf16* h0 = (__bf16*)(ws + 2359296);
    __bf16* h1 = (__bf16*)(ws + 2359296 + 1048576);
    unsigned int* bar = (unsigned int*)(ws + 2359296 + 2 * 1048576);

    hipMemsetAsync(h0, 0, 1048576, stream);   // t=0 reads h0 as zeros
    hipMemsetAsync(bar, 0, 2048, stream);     // monotonic barrier counters

    const int total = G4n * Kn;
    convert_weights<<<(total + 255) / 256, 256, 0, stream>>>(Wih, Whh, Wc);

    lstm_persist<<<256, 256, 0, stream>>>(xd, b, Wc, h0, h1, bar);

    // t=729 (odd) writes h0 -> final hidden state is in h0
    head_kernel<<<Bn, 64, 0, stream>>>(h0, Wl, bl, out);
}

// Round 2
// 5499.720 us; speedup vs baseline: 1.9358x; 1.9358x over previous
//
#include <hip/hip_runtime.h>
#include <hip/hip_bf16.h>

#define Bn   1024
#define Tn   730
#define INn  64
#define Hn   512
#define Kn   576      // INn + Hn
#define G4n  2048     // 4*Hn

typedef __bf16 bf16x8 __attribute__((ext_vector_type(8)));
typedef float  f32x4  __attribute__((ext_vector_type(4)));

// zT exchange layout: [64 rows][8 sections(g,ks) x 36] with row stride 300 floats
// (300 mod 32 = 12 — same low-conflict residue family as the measured round-1 layout).
#define ZSTR 300
#define SSTR 36

// ---------------- weight pre-pack: Wc[row][k] bf16, row = gate*512+j, k over [x|h] ----------
__global__ void convert_weights(const float* __restrict__ Wih,
                                const float* __restrict__ Whh,
                                __bf16* __restrict__ Wc) {
    int idx = blockIdx.x * 256 + threadIdx.x;
    if (idx >= G4n * Kn) return;
    int row = idx / Kn;
    int k   = idx - row * Kn;
    float v = (k < INn) ? Wih[row * INn + k] : Whh[row * Hn + (k - INn)];
    Wc[idx] = (__bf16)v;
}

__device__ __forceinline__ float sigf(float x)   { return 1.0f / (1.0f + __expf(-x)); }
__device__ __forceinline__ float tanhf_f(float x){ return 2.0f * sigf(2.0f * x) - 1.0f; }

// ---------------- persistent LSTM scan ----------------
// 256 blocks x 512 threads (8 waves). Block = (mi: 64 batch rows) x (nj: 32 h-cols).
// SPLIT-K: wave w -> (gate g = w>>1, k-half ks = w&1). Each wave: 32 cols x K/2
// in 72 weight VGPRs, reads only its K-half of the A-tile (36 ds_read_b128 vs 72)
// -> phase-2 LDS traffic halved vs round-0. Halves summed in the zT exchange.
// h staging: relaxed agent-scope u64 atomic loads (IC write-through path, proven),
// all 16 loads issued before any ds_write so IC latency overlaps.
// Barrier: per-group (16 blocks sharing mi) monotonic counter at IC, round-0 scheme.
__global__ __launch_bounds__(512, 1) void lstm_persist(
    const float* __restrict__ xd,     // [B,T,IN]
    const float* __restrict__ bias,   // [4H]
    const __bf16* __restrict__ Wc,    // [4H][Kn]
    __bf16* __restrict__ h0,          // [B,H] buffer A (final h lands here)
    __bf16* __restrict__ h1,          // [B,H] buffer B
    unsigned int* __restrict__ bar)   // 16 groups x 32 uints (128B stride)
{
    // LDS: A-tile (fragment order) 73728 B + zT 64*300*4 = 76800 B -> 150528 B (1 block/CU)
    __shared__ __align__(16) char smem[73728 + ZSTR * 64 * 4];
    bf16x8* aTile = (bf16x8*)smem;
    float*  zT    = (float*)(smem + 73728);

    const int blk  = blockIdx.x;
    const int xcd  = blk & 7;
    const int slot = blk >> 3;
    const int mi   = xcd * 2 + (slot & 1);
    const int nj   = slot >> 1;
    const int m0   = mi << 6;
    const int j0   = nj << 5;

    const int tid  = threadIdx.x;              // 0..511
    const int wave = tid >> 6;                 // 0..7
    const int lane = tid & 63;
    const int q    = lane >> 4;
    const int l16  = lane & 15;

    const int g  = wave >> 1;                  // gate 0..3
    const int ks = wave & 1;                   // k-half 0..1

    // ---- resident weights: gate g, cols j0 + js*16 + l16, k-blocks ks*9..ks*9+8 ----
    bf16x8 wreg[9][2];
    #pragma unroll
    for (int kb = 0; kb < 9; ++kb) {
        #pragma unroll
        for (int js = 0; js < 2; ++js)
            wreg[kb][js] = *(const bf16x8*)(Wc + (size_t)(g * Hn + j0 + js * 16 + l16) * Kn
                                               + (ks * 9 + kb) * 32 + q * 8);
    }
    // bias folded into ks=0 accumulator init (per-lane output column, same for all rows)
    const float bini0 = ks ? 0.f : bias[g * Hn + j0 + l16];
    const float bini1 = ks ? 0.f : bias[g * Hn + j0 + 16 + l16];

    // ---- pointwise ownership: thread -> (1 row, 4 consecutive cols) ----
    const int pr   = tid >> 3;                 // 0..63
    const int pc4  = (tid & 7) << 2;           // 0..28
    const int prow = m0 + pr;
    float creg[4] = {0.f, 0.f, 0.f, 0.f};

    // ---- staging bases (all shift/mask, no div) ----
    // h fragments: thread stages 8 frags: rg = i>>1, kb = 2 + wave + 8*(i&1)
    const int hoff_c = (m0 + l16) * Hn + wave * 32 + q * 8;   // + (i>>1)*8192 + (i&1)*256
    const int haslot = (2 + wave) * 64 + lane;                // + (i>>1)*1152 + (i&1)*512
    // x fragment: thread's wave stages frag (rg=g, kb=ks)
    const float* xrb  = xd + (size_t)(m0 + g * 16 + l16) * (Tn * INn) + ks * 32 + q * 8;
    const int    xslot = (g * 18 + ks) * 64 + lane;

    unsigned int* cnt = bar + (mi << 5);       // one 128B line per group
    bool dead = false;

    // ---- prologue: stage x(t=0) ----
    {
        f32x4 lo = *(const f32x4*)xrb;
        f32x4 hi = *(const f32x4*)(xrb + 4);
        bf16x8 v;
        v[0] = (__bf16)lo[0]; v[1] = (__bf16)lo[1]; v[2] = (__bf16)lo[2]; v[3] = (__bf16)lo[3];
        v[4] = (__bf16)hi[0]; v[5] = (__bf16)hi[1]; v[6] = (__bf16)hi[2]; v[7] = (__bf16)hi[3];
        aTile[xslot] = v;
    }

    for (int t = 0; t < Tn; ++t) {
        const __bf16* hread  = (t & 1) ? h1 : h0;
        __bf16*       hwrite = (t & 1) ? h0 : h1;

        // ---- phase 1: h -> regs (16 u64 loads all in flight), then -> LDS ----
        unsigned long long hu[8][2];
        #pragma unroll
        for (int i = 0; i < 8; ++i) {
            const unsigned long long* hp =
                (const unsigned long long*)(hread + hoff_c + (i >> 1) * 8192 + (i & 1) * 256);
            hu[i][0] = __hip_atomic_load(hp,     __ATOMIC_RELAXED, __HIP_MEMORY_SCOPE_AGENT);
            hu[i][1] = __hip_atomic_load(hp + 1, __ATOMIC_RELAXED, __HIP_MEMORY_SCOPE_AGENT);
        }
        #pragma unroll
        for (int i = 0; i < 8; ++i) {
            union { unsigned long long u[2]; bf16x8 v; } cv;
            cv.u[0] = hu[i][0]; cv.u[1] = hu[i][1];
            aTile[haslot + (i >> 1) * 1152 + (i & 1) * 512] = cv.v;
        }
        __syncthreads();

        // ---- phase 2: MFMA over this wave's K-half; weights in regs, A from LDS ----
        f32x4 acc[4][2];
        #pragma unroll
        for (int rg = 0; rg < 4; ++rg) {
            acc[rg][0] = (f32x4){bini0, bini0, bini0, bini0};
            acc[rg][1] = (f32x4){bini1, bini1, bini1, bini1};
        }
        #pragma unroll
        for (int kb = 0; kb < 9; ++kb) {
            #pragma unroll
            for (int rg = 0; rg < 4; ++rg) {
                const bf16x8 af = aTile[(rg * 18 + ks * 9 + kb) * 64 + lane];
                acc[rg][0] = __builtin_amdgcn_mfma_f32_16x16x32_bf16(af, wreg[kb][0], acc[rg][0], 0, 0, 0);
                acc[rg][1] = __builtin_amdgcn_mfma_f32_16x16x32_bf16(af, wreg[kb][1], acc[rg][1], 0, 0, 0);
            }
        }

        // ---- phase 3: z scatter to zT (scalar, 2-way-free banks) ----
        #pragma unroll
        for (int rg = 0; rg < 4; ++rg) {
            #pragma unroll
            for (int js = 0; js < 2; ++js) {
                #pragma unroll
                for (int r = 0; r < 4; ++r)
                    zT[(rg * 16 + q * 4 + r) * ZSTR + (g * 2 + ks) * SSTR + js * 16 + l16]
                        = acc[rg][js][r];
            }
        }
        __syncthreads();

        // ---- phase 4: issue x(t+1) loads; pointwise under their latency ----
        f32x4 xlo, xhi;
        const bool do_x = (t + 1 < Tn);
        if (do_x) {
            const float* xp = xrb + (size_t)(t + 1) * INn;
            xlo = *(const f32x4*)xp;
            xhi = *(const f32x4*)(xp + 4);
        }

        // gate pointwise: vector gather of both K-halves, sum, activate
        float zv[4][4];
        #pragma unroll
        for (int gg = 0; gg < 4; ++gg) {
            f32x4 v0 = *(const f32x4*)&zT[pr * ZSTR + (gg * 2 + 0) * SSTR + pc4];
            f32x4 v1 = *(const f32x4*)&zT[pr * ZSTR + (gg * 2 + 1) * SSTR + pc4];
            f32x4 s  = v0 + v1;
            zv[gg][0] = s[0]; zv[gg][1] = s[1]; zv[gg][2] = s[2]; zv[gg][3] = s[3];
        }
        union { unsigned long long u; __bf16 h[4]; } pk;
        #pragma unroll
        for (int cc = 0; cc < 4; ++cc) {
            const float cn = sigf(zv[1][cc]) * creg[cc]
                           + sigf(zv[0][cc]) * tanhf_f(zv[2][cc]);
            creg[cc] = cn;
            pk.h[cc] = (__bf16)(sigf(zv[3][cc]) * tanhf_f(cn));
        }
        __hip_atomic_store((unsigned long long*)(hwrite + (size_t)prow * Hn + j0 + pc4),
                           pk.u, __ATOMIC_RELAXED, __HIP_MEMORY_SCOPE_AGENT);

        // finish x(t+1) staging (loads have had the gate math to land)
        if (do_x) {
            bf16x8 v;
            v[0] = (__bf16)xlo[0]; v[1] = (__bf16)xlo[1]; v[2] = (__bf16)xlo[2]; v[3] = (__bf16)xlo[3];
            v[4] = (__bf16)xhi[0]; v[5] = (__bf16)xhi[1]; v[6] = (__bf16)xhi[2]; v[7] = (__bf16)xhi[3];
            aTile[xslot] = v;
        }

        // ---- phase 5: group barrier (16 blocks sharing mi), relaxed atomics only ----
        __syncthreads();   // drains vmcnt(0): all write-through h stores at IC
        if (tid == 0) {
            __hip_atomic_fetch_add(cnt, 1u, __ATOMIC_RELAXED, __HIP_MEMORY_SCOPE_AGENT);
            if (!dead) {
                const unsigned int target = 16u * (unsigned int)(t + 1);
                int spins = 0;
                while (__hip_atomic_load(cnt, __ATOMIC_RELAXED, __HIP_MEMORY_SCOPE_AGENT) < target) {
                    __builtin_amdgcn_s_sleep(2);
                    if (++spins > 300000) { dead = true; break; }  // hang -> fast wrong-answer
                }
            }
        }
        __syncthreads();
    }
}

// ---------------- head: out[b] = relu(dot(h_T[b], Wl) + bl) ----------------
__global__ void head_kernel(const __bf16* __restrict__ h, const float* __restrict__ Wl,
                            const float* __restrict__ bl, float* __restrict__ out) {
    const int b = blockIdx.x;
    const int lane = threadIdx.x;  // 64 threads
    const __bf16* hp = h + (size_t)b * Hn;
    float s = 0.f;
    #pragma unroll
    for (int j = lane; j < Hn; j += 64) s += (float)hp[j] * Wl[j];
    #pragma unroll
    for (int off = 32; off > 0; off >>= 1) s += __shfl_down(s, off, 64);
    if (lane == 0) out[b] = fmaxf(s + bl[0], 0.0f);
}

extern "C" void kernel_launch(void* const* d_in, const int* in_sizes, int n_in,
                              void* d_out, int out_size, void* d_ws, size_t ws_size,
                              hipStream_t stream) {
    const float* xd  = (const float*)d_in[0];
    const float* Wih = (const float*)d_in[1];
    const float* Whh = (const float*)d_in[2];
    const float* b   = (const float*)d_in[3];
    const float* Wl  = (const float*)d_in[4];
    const float* bl  = (const float*)d_in[5];
    float* out = (float*)d_out;

    // ws layout:
    //   Wc  bf16 [2048][576] : 2,359,296 B
    //   h0  bf16 [1024][512] : 1,048,576 B
    //   h1  bf16 [1024][512] : 1,048,576 B
    //   bar u32  [16][32]    : 2,048 B
    char* ws = (char*)d_ws;
    __bf16* Wc = (__bf16*)ws;
    __bf16* h0 = (__bf16*)(ws + 2359296);
    __bf16* h1 = (__bf16*)(ws + 2359296 + 1048576);
    unsigned int* bar = (unsigned int*)(ws + 2359296 + 2 * 1048576);

    hipMemsetAsync(h0, 0, 1048576, stream);   // t=0 reads h0 as zeros
    hipMemsetAsync(bar, 0, 2048, stream);     // monotonic barrier counters

    const int total = G4n * Kn;
    convert_weights<<<(total + 255) / 256, 256, 0, stream>>>(Wih, Whh, Wc);

    lstm_persist<<<256, 512, 0, stream>>>(xd, b, Wc, h0, h1, bar);

    // t=729 (odd) writes h0 -> final hidden state is in h0
    head_kernel<<<Bn, 64, 0, stream>>>(h0, Wl, bl, out);
}